// Round 13
// baseline (265.011 us; speedup 1.0000x reference)
//
#include <hip/hip_runtime.h>
#include <hip/hip_bf16.h>

constexpr int BATCH = 8;
constexpr int N = 2048;
constexpr int D = 512;
constexpr int NBLK = 136;   // upper-triangular 16x16 block pairs

using short8 = __attribute__((ext_vector_type(8))) short;
using half8 = __attribute__((ext_vector_type(8))) _Float16;
using floatx4 = __attribute__((ext_vector_type(4))) float;

struct f8 { float4 a, b; };
__device__ __forceinline__ f8 load8(const float* p) {
    f8 r; r.a = *(const float4*)p; r.b = *(const float4*)(p + 4); return r;
}
// fp32 -> fp16 (h,l) Dekker split: x = h + l + eps, eps ~ 2^-22 |x|
__device__ __forceinline__ void cvt_split(const f8& v, short8& h, short8& l) {
    const float* f = (const float*)&v;
#pragma unroll
    for (int e = 0; e < 8; ++e) {
        _Float16 hh = (_Float16)f[e];            // RNE
        float r = f[e] - (float)hh;              // exact in fp32
        _Float16 ll = (_Float16)r;
        h[e] = __builtin_bit_cast(short, hh);
        l[e] = __builtin_bit_cast(short, ll);
    }
}

// ---------------------------------------------------------------------------
// Kernel 0: per-batch prefix sum of boundaries -> community ids,
//           zero stats accumulators and per-batch ticket counters.
// ---------------------------------------------------------------------------
__global__ __launch_bounds__(256) void scan_kernel(const int* __restrict__ b,
                                                   int* __restrict__ comm,
                                                   float* __restrict__ stats /*3*BATCH*N*/,
                                                   int* __restrict__ tickets /*BATCH*/) {
    int batch = blockIdx.x;
    int t = threadIdx.x;

    {   // zero ssq|sm|bs: 3*8*2048 floats over 8 blocks x 256 threads = 24 each
        int idx = batch * 256 + t;
#pragma unroll
        for (int u = 0; u < 24; ++u) stats[idx + u * 2048] = 0.0f;
    }
    if (t == 0) tickets[batch] = 0;

    const int* bb = b + batch * N;
    int* cc = comm + batch * N;
    int vals[8];
    int s = 0;
#pragma unroll
    for (int u = 0; u < 8; ++u) { vals[u] = bb[t * 8 + u]; s += vals[u]; }

    __shared__ int ps[256];
    ps[t] = s;
    __syncthreads();
    for (int off = 1; off < 256; off <<= 1) {
        int v = (t >= off) ? ps[t - off] : 0;
        __syncthreads();
        ps[t] += v;
        __syncthreads();
    }
    int run = (t > 0) ? ps[t - 1] : 0;
#pragma unroll
    for (int u = 0; u < 8; ++u) { run += vals[u]; cc[t * 8 + u] = run; }
}

// ---------------------------------------------------------------------------
// Kernel 1: MFMA fp16-split G = R*R^T, symmetric (upper-triangular pairs),
//   fused fp32->fp16 conversion in staging, fused per-row stats, and fused
//   per-batch FINALIZE: the 136th block of each batch (threadfence-reduction
//   ticket) computes modularity+conductance inline, reusing staging LDS.
//   launch_bounds(256,3): cap unified VGPR+AGPR at ~170 (need 116+64=180 ->
//   trim ~10; r8 showed cap 128 = catastrophic spill, r12 showed no cap = 2
//   waves/SIMD only).
// ---------------------------------------------------------------------------
__global__ __launch_bounds__(256, 3) void gemm_mfma(
        const float* __restrict__ R,
        const int* __restrict__ comm,
        float* __restrict__ ssq, float* __restrict__ sm, float* __restrict__ bs,
        int* __restrict__ tickets,
        float* __restrict__ out) {
    int batch = blockIdx.z;

    // decode triangular pair index -> (bi, bj), bi <= bj
    int tt = blockIdx.x;
    int bi = 0;
    while (tt >= (16 - bi)) { tt -= (16 - bi); ++bi; }
    int bj = bi + tt;
    bool diag = (bi == bj);
    int i0 = bi * 128, j0 = bj * 128;

    // flat 32KB staging LDS: Ahi@0, Alo@8192, Bhi@16384, Blo@24576 (bytes).
    // Reused by the inline finalize as community bins after the K-loop.
    __shared__ __align__(16) unsigned char SMEM[32768];
    __shared__ int sci[128], scj[128];
    __shared__ int sIsLast;

    int tid = threadIdx.x;
    const int* cm = comm + batch * N;
    if (tid < 128) { sci[tid] = cm[i0 + tid]; scj[tid] = cm[j0 + tid]; }

    const size_t bo = (size_t)batch * N * D;
    int srow = tid >> 2;                         // 0..63 (row within half-tile)
    int kg = (tid & 3) ^ ((srow >> 1) & 3);      // pre-swizzled source k-group
    const float* pA0 = R + bo + (size_t)(i0 + srow) * D + kg * 8;
    const float* pA1 = pA0 + (size_t)64 * D;
    const float* pB0 = R + bo + (size_t)(j0 + srow) * D + kg * 8;
    const float* pB1 = pB0 + (size_t)64 * D;

    int lane = tid & 63;
    int wv = tid >> 6;
    int wrow = wv >> 1, wcol = wv & 1;           // 2x2 waves of 64x64
    int l15 = lane & 15, lhi = lane >> 4;

    // fragment LDS byte offsets within one 8KB array (fixed across k-steps)
    int offA[4], offB[4];
#pragma unroll
    for (int m = 0; m < 4; ++m) {
        int r = wrow * 64 + m * 16 + l15;
        offA[m] = r * 64 + ((lhi ^ ((r >> 1) & 3)) << 4);
        int c = wcol * 64 + m * 16 + l15;
        offB[m] = c * 64 + ((lhi ^ ((c >> 1) & 3)) << 4);
    }

    floatx4 acc[4][4];
#pragma unroll
    for (int m = 0; m < 4; ++m)
#pragma unroll
        for (int n = 0; n < 4; ++n) acc[m][n] = (floatx4){0.f, 0.f, 0.f, 0.f};

    int wbyte = tid * 16;                        // linear ds_write offset

    // prologue: load tile 0 (fp32) into registers
    f8 rA0 = load8(pA0), rA1 = load8(pA1), rB0 = load8(pB0), rB1 = load8(pB1);

#pragma unroll 1
    for (int kt = 0; kt < 16; ++kt) {
        // convert + stage current tile to LDS
        short8 h, l;
        cvt_split(rA0, h, l);
        *(short8*)(SMEM + wbyte) = h;
        *(short8*)(SMEM + 8192 + wbyte) = l;
        cvt_split(rA1, h, l);
        *(short8*)(SMEM + 4096 + wbyte) = h;
        *(short8*)(SMEM + 8192 + 4096 + wbyte) = l;
        cvt_split(rB0, h, l);
        *(short8*)(SMEM + 16384 + wbyte) = h;
        *(short8*)(SMEM + 24576 + wbyte) = l;
        cvt_split(rB1, h, l);
        *(short8*)(SMEM + 16384 + 4096 + wbyte) = h;
        *(short8*)(SMEM + 24576 + 4096 + wbyte) = l;
        __syncthreads();

        // issue next tile's global loads (latency hides under MFMA below)
        if (kt < 15) {
            int ko = (kt + 1) * 32;
            rA0 = load8(pA0 + ko);
            rA1 = load8(pA1 + ko);
            rB0 = load8(pB0 + ko);
            rB1 = load8(pB1 + ko);
        }

        half8 ah[4], al[4], bh[4], bl[4];
#pragma unroll
        for (int m = 0; m < 4; ++m) {
            ah[m] = *(const half8*)(SMEM + offA[m]);
            al[m] = *(const half8*)(SMEM + 8192 + offA[m]);
            bh[m] = *(const half8*)(SMEM + 16384 + offB[m]);
            bl[m] = *(const half8*)(SMEM + 24576 + offB[m]);
        }
#pragma unroll
        for (int m = 0; m < 4; ++m)
#pragma unroll
            for (int n = 0; n < 4; ++n) {
                acc[m][n] = __builtin_amdgcn_mfma_f32_16x16x32_f16(ah[m], bh[n], acc[m][n], 0, 0, 0);
                acc[m][n] = __builtin_amdgcn_mfma_f32_16x16x32_f16(ah[m], bl[n], acc[m][n], 0, 0, 0);
                acc[m][n] = __builtin_amdgcn_mfma_f32_16x16x32_f16(al[m], bh[n], acc[m][n], 0, 0, 0);
            }
        __syncthreads();
    }

    // epilogue: row stats + column stats for mirror rows when off-diagonal
    // (G symmetric; hh+hl+lh is symmetric).
    float* pssq = ssq + batch * N;
    float* psm = sm + batch * N;
    float* pbs = bs + batch * N;

    int cjv[4];
#pragma unroll
    for (int n = 0; n < 4; ++n) cjv[n] = scj[wcol * 64 + n * 16 + l15];

    float cq[4] = {0.f, 0.f, 0.f, 0.f};
    float cs[4] = {0.f, 0.f, 0.f, 0.f};
    float cb[4] = {0.f, 0.f, 0.f, 0.f};

#pragma unroll
    for (int m = 0; m < 4; ++m) {
#pragma unroll
        for (int rr = 0; rr < 4; ++rr) {
            int rloc = wrow * 64 + m * 16 + lhi * 4 + rr;   // C layout: row=(l>>4)*4+reg
            int civ = sci[rloc];
            float vq = 0.f, vs = 0.f, vb = 0.f;
#pragma unroll
            for (int n = 0; n < 4; ++n) {
                float g = acc[m][n][rr];
                float gq = g * g;
                float gb = (civ == cjv[n]) ? g : 0.f;
                vq += gq; vs += g; vb += gb;
                cq[n] += gq; cs[n] += g; cb[n] += gb;
            }
#pragma unroll
            for (int msk = 8; msk >= 1; msk >>= 1) {
                vq += __shfl_xor(vq, msk);
                vs += __shfl_xor(vs, msk);
                vb += __shfl_xor(vb, msk);
            }
            if (l15 == 0) {
                atomicAdd(&pssq[i0 + rloc], vq);
                atomicAdd(&psm[i0 + rloc], vs);
                atomicAdd(&pbs[i0 + rloc], vb);
            }
        }
    }

    if (!diag) {
#pragma unroll
        for (int n = 0; n < 4; ++n) {
            cq[n] += __shfl_xor(cq[n], 16); cq[n] += __shfl_xor(cq[n], 32);
            cs[n] += __shfl_xor(cs[n], 16); cs[n] += __shfl_xor(cs[n], 32);
            cb[n] += __shfl_xor(cb[n], 16); cb[n] += __shfl_xor(cb[n], 32);
            if (lhi == 0) {
                int col = j0 + wcol * 64 + n * 16 + l15;
                atomicAdd(&pssq[col], cq[n]);
                atomicAdd(&psm[col], cs[n]);
                atomicAdd(&pbs[col], cb[n]);
            }
        }
    }

    // -------- ticket: last block of this batch runs the finalize inline ----
    __threadfence();                // release our stats atomics device-wide
    __syncthreads();                // all threads' atomics drained (vmcnt)
    if (tid == 0) {
        int old = atomicAdd(&tickets[batch], 1);
        sIsLast = (old == NBLK - 1);
    }
    __syncthreads();
    if (!sIsLast) return;

    // ---- inline per-batch finalize (256 threads), bins reuse SMEM --------
    float* fWc = (float*)SMEM;                    // 2049 floats
    float* fTc = (float*)(SMEM + 2064 * 4);       // 2049 floats
    int* fCnt = (int*)(SMEM + 4128 * 4);          // 2049 ints
    float* red = (float*)(SMEM + 6192 * 4);       // 5x4 partials

    for (int c = tid; c < N + 1; c += 256) { fWc[c] = 0.f; fTc[c] = 0.f; fCnt[c] = 0; }
    __syncthreads();

    float totalLocal = 0.f;
    for (int i = tid; i < N; i += 256) {
        // atomic reads: coherent with writers' device-scope atomics
        float q = atomicAdd(&pssq[i], 0.0f);
        float s = atomicAdd(&psm[i], 0.0f);
        float b = atomicAdd(&pbs[i], 0.0f);
        float r = fmaxf(sqrtf(q), 1e-12f);
        float deg = s / r;
        float bn = b / r;
        int c = cm[i];
        atomicAdd(&fTc[c], deg);
        atomicAdd(&fWc[c], bn);
        atomicAdd(&fCnt[c], 1);
        totalLocal += deg;
    }
    __syncthreads();

    float sumW = 0.f, sumT2 = 0.f, condSum = 0.f, ncomm = 0.f;
    for (int c = tid; c < N + 1; c += 256) {
        if (fCnt[c] > 0) {
            float W = fWc[c];
            float T = fTc[c];
            sumW += W;
            sumT2 += T * T;
            float between = T - W;
            condSum += between / (2.0f * W + between + 1e-10f);
            ncomm += 1.0f;
        }
    }

    float vals[5] = {totalLocal, sumW, sumT2, condSum, ncomm};
#pragma unroll
    for (int v = 0; v < 5; ++v)
#pragma unroll
        for (int msk = 32; msk >= 1; msk >>= 1) vals[v] += __shfl_xor(vals[v], msk);
    __syncthreads();
    if ((tid & 63) == 0) {
#pragma unroll
        for (int v = 0; v < 5; ++v) red[v * 4 + (tid >> 6)] = vals[v];
    }
    __syncthreads();
    if (tid == 0) {
        float r5[5];
#pragma unroll
        for (int v = 0; v < 5; ++v)
            r5[v] = red[v * 4] + red[v * 4 + 1] + red[v * 4 + 2] + red[v * 4 + 3];
        float total = r5[0];
        out[batch] = (r5[1] - r5[2] / total) / total;               // modularity
        out[BATCH + batch] = r5[3] / fmaxf(r5[4], 1.0f);            // conductance
    }
}

// ---------------------------------------------------------------------------
extern "C" void kernel_launch(void* const* d_in, const int* in_sizes, int n_in,
                              void* d_out, int out_size, void* d_ws, size_t ws_size,
                              hipStream_t stream) {
    const float* rep = (const float*)d_in[0];
    const int* bnd = (const int*)d_in[1];
    float* out = (float*)d_out;

    // ws layout: ssq | sm | bs | comm | tickets
    float* ssq = (float*)d_ws;
    float* sm = ssq + BATCH * N;
    float* bs = sm + BATCH * N;
    int* comm = (int*)(bs + BATCH * N);
    int* tickets = comm + BATCH * N;

    scan_kernel<<<BATCH, 256, 0, stream>>>(bnd, comm, ssq, tickets);

    dim3 grid(NBLK, 1, BATCH);   // upper-triangular block pairs
    gemm_mfma<<<grid, 256, 0, stream>>>(rep, comm, ssq, sm, bs, tickets, out);
}